// Round 4
// baseline (507.422 us; speedup 1.0000x reference)
//
#include <hip/hip_runtime.h>

// Problem dims (fixed by the reference)
#define BB 8
#define SS 4096
#define TT 512
#define DD 1024

typedef __attribute__((ext_vector_type(8))) short bf16x8;   // 8 bf16 = 16B
typedef __attribute__((ext_vector_type(4))) float f32x4;

__device__ inline unsigned short f2bf(float f) {
  unsigned int u = __float_as_uint(f);
  u += 0x7FFFu + ((u >> 16) & 1u);   // round-to-nearest-even
  return (unsigned short)(u >> 16);
}
// pack 16 consecutive f32 -> two bf16x8 (16B-aligned dst)
__device__ inline void pack16(const float* __restrict__ src, short* __restrict__ dst) {
  f32x4 f0 = *(const f32x4*)(src + 0);
  f32x4 f1 = *(const f32x4*)(src + 4);
  f32x4 f2 = *(const f32x4*)(src + 8);
  f32x4 f3 = *(const f32x4*)(src + 12);
  bf16x8 b0, b1;
  b0[0] = (short)f2bf(f0.x); b0[1] = (short)f2bf(f0.y);
  b0[2] = (short)f2bf(f0.z); b0[3] = (short)f2bf(f0.w);
  b0[4] = (short)f2bf(f1.x); b0[5] = (short)f2bf(f1.y);
  b0[6] = (short)f2bf(f1.z); b0[7] = (short)f2bf(f1.w);
  b1[0] = (short)f2bf(f2.x); b1[1] = (short)f2bf(f2.y);
  b1[2] = (short)f2bf(f2.z); b1[3] = (short)f2bf(f2.w);
  b1[4] = (short)f2bf(f3.x); b1[5] = (short)f2bf(f3.y);
  b1[6] = (short)f2bf(f3.z); b1[7] = (short)f2bf(f3.w);
  *(bf16x8*)(dst + 0) = b0;
  *(bf16x8*)(dst + 8) = b1;
}

// ---------------------------------------------------------------------------
// Kernel 1: scores = Q @ C^T / sqrt(D) -> f32 into p region.
// A = query [T,D] f32 (K-contig), Bt = ctx [S,D] f32 (K-contig).
// 128x128 tile, BK=32, 256 threads = 4 waves, each wave 64x64 (4x4 frags).
// ---------------------------------------------------------------------------
__global__ __launch_bounds__(256) void qk_kernel(const float* __restrict__ q,
                                                 const float* __restrict__ c,
                                                 float* __restrict__ p) {
  const int b  = blockIdx.z;
  const int m0 = blockIdx.y * 128;   // T dim
  const int n0 = blockIdx.x * 128;   // S dim
  const float* A  = q + (size_t)b * TT * DD;
  const float* Bt = c + (size_t)b * SS * DD;

  __shared__ alignas(16) short As[128 * 40];   // row stride 40 (80B, 16B mult)
  __shared__ alignas(16) short Bs[128 * 40];

  const int tid  = threadIdx.x;
  const int wave = tid >> 6, lane = tid & 63;
  const int quad = lane >> 4, l16 = lane & 15;
  const int wm = (wave >> 1) * 64, wn = (wave & 1) * 64;

  f32x4 acc[4][4];
#pragma unroll
  for (int i = 0; i < 4; ++i)
#pragma unroll
    for (int j = 0; j < 4; ++j) acc[i][j] = (f32x4){0.f, 0.f, 0.f, 0.f};

  const int ar = tid >> 1;          // row 0..127
  const int ak = (tid & 1) * 16;    // k-half 0 or 16

  for (int k0 = 0; k0 < DD; k0 += 32) {
    __syncthreads();
    pack16(A  + (size_t)(m0 + ar) * DD + k0 + ak, &As[ar * 40 + ak]);
    pack16(Bt + (size_t)(n0 + ar) * DD + k0 + ak, &Bs[ar * 40 + ak]);
    __syncthreads();

    bf16x8 af[4], bfv[4];
#pragma unroll
    for (int i = 0; i < 4; ++i)
      af[i] = *(const bf16x8*)&As[(wm + i * 16 + l16) * 40 + quad * 8];
#pragma unroll
    for (int j = 0; j < 4; ++j)
      bfv[j] = *(const bf16x8*)&Bs[(wn + j * 16 + l16) * 40 + quad * 8];
#pragma unroll
    for (int i = 0; i < 4; ++i)
#pragma unroll
      for (int j = 0; j < 4; ++j)
        acc[i][j] = __builtin_amdgcn_mfma_f32_16x16x32_bf16(af[i], bfv[j],
                                                            acc[i][j], 0, 0, 0);
  }

  // C/D layout (m89-verified): col=lane&15 (N), row=quad*4+reg (M).
  float* P = p + (size_t)b * TT * SS;
#pragma unroll
  for (int i = 0; i < 4; ++i)
#pragma unroll
    for (int j = 0; j < 4; ++j)
#pragma unroll
      for (int r = 0; r < 4; ++r) {
        const int row = m0 + wm + i * 16 + quad * 4 + r;
        const int col = n0 + wn + j * 16 + l16;
        P[(size_t)row * SS + col] = acc[i][j][r] * 0.03125f;  // 1/sqrt(1024)
      }
}

// ---------------------------------------------------------------------------
// Kernel 2: masked softmax over S, in place on the f32 p region.
// One 256-thread block per (b, t) row; 16 f32/thread via float4.
// ---------------------------------------------------------------------------
__global__ __launch_bounds__(256) void softmax_kernel(float* __restrict__ p,
                                                      const int* __restrict__ mask) {
  const int row = blockIdx.x;           // b*T + t
  const int b   = row >> 9;             // / 512  (T = 512)
  float* pr = p + (size_t)row * SS;
  const int* mr = mask + b * SS;
  const int tid = threadIdx.x;
  const int wave = tid >> 6, lane = tid & 63;

  float v[16];
  float mx = -3.0e38f;
#pragma unroll
  for (int h = 0; h < 4; ++h) {
    const int base = tid * 4 + h * 1024;
    f32x4 s = *(const f32x4*)(pr + base);
    const int4 m4 = *(const int4*)(mr + base);
#pragma unroll
    for (int j = 0; j < 4; ++j) {
      float f = (j == 0 ? s.x : j == 1 ? s.y : j == 2 ? s.z : s.w);
      const int mk = (j == 0 ? m4.x : j == 1 ? m4.y : j == 2 ? m4.z : m4.w);
      f = fminf(fmaxf(f, -1.0e30f), 1.0e30f);   // scrub NaN/inf (no-op on sane)
      f = (mk == 0) ? -10000.0f : f;
      v[h * 4 + j] = f;
      mx = fmaxf(mx, f);
    }
  }
#pragma unroll
  for (int off = 32; off > 0; off >>= 1) mx = fmaxf(mx, __shfl_down(mx, off));
  __shared__ float red[4];
  if (lane == 0) red[wave] = mx;
  __syncthreads();
  mx = fmaxf(fmaxf(red[0], red[1]), fmaxf(red[2], red[3]));
  __syncthreads();

  float e[16];
  float sum = 0.f;
#pragma unroll
  for (int k = 0; k < 16; ++k) { e[k] = __expf(v[k] - mx); sum += e[k]; }
#pragma unroll
  for (int off = 32; off > 0; off >>= 1) sum += __shfl_down(sum, off);
  if (lane == 0) red[wave] = sum;
  __syncthreads();
  const float inv = 1.0f / (red[0] + red[1] + red[2] + red[3]);

#pragma unroll
  for (int h = 0; h < 4; ++h) {
    const int base = tid * 4 + h * 1024;
    f32x4 o;
    o.x = e[h * 4 + 0] * inv;
    o.y = e[h * 4 + 1] * inv;
    o.z = e[h * 4 + 2] * inv;
    o.w = e[h * 4 + 3] * inv;
    *(f32x4*)(pr + base) = o;
  }
}

// ---------------------------------------------------------------------------
// Kernel 3: expected = P @ C -> f32.  A = p [T,S] f32 (K-contig, bf16-packed
// during staging), B = ctx [S,D] f32 (N-contig -> bf16-transpose staging).
// ---------------------------------------------------------------------------
__global__ __launch_bounds__(256) void pv_kernel(const float* __restrict__ p,
                                                 const float* __restrict__ c,
                                                 float* __restrict__ e) {
  const int b  = blockIdx.z;
  const int m0 = blockIdx.y * 128;   // T dim
  const int n0 = blockIdx.x * 128;   // D dim
  const float* A  = p + (size_t)b * TT * SS;
  const float* Bm = c + (size_t)b * SS * DD;

  __shared__ alignas(16) short As[128 * 40];
  __shared__ alignas(16) short Bs[128 * 40];   // Bs[n][k] (transposed)

  const int tid  = threadIdx.x;
  const int wave = tid >> 6, lane = tid & 63;
  const int quad = lane >> 4, l16 = lane & 15;
  const int wm = (wave >> 1) * 64, wn = (wave & 1) * 64;

  f32x4 acc[4][4];
#pragma unroll
  for (int i = 0; i < 4; ++i)
#pragma unroll
    for (int j = 0; j < 4; ++j) acc[i][j] = (f32x4){0.f, 0.f, 0.f, 0.f};

  const int ar = tid >> 1;          // A row 0..127
  const int ak = (tid & 1) * 16;    // A k-half 0 or 16
  const int kk = tid >> 3;          // B k-row 0..31
  const int c0 = (tid & 7) * 16;    // B col base (16 cols/thread)

  for (int k0 = 0; k0 < SS; k0 += 32) {
    __syncthreads();
    // A tile: [128 x 32] f32 -> bf16 pack.
    pack16(A + (size_t)(m0 + ar) * SS + k0 + ak, &As[ar * 40 + ak]);
    // B tile: ctx rows k0..k0+31 (f32), cols n0..n0+127 -> Bs[n][k] bf16.
    {
      const float* bp = Bm + (size_t)(k0 + kk) * DD + n0 + c0;
#pragma unroll
      for (int h = 0; h < 4; ++h) {
        f32x4 f = *(const f32x4*)(bp + h * 4);
        Bs[(c0 + h * 4 + 0) * 40 + kk] = (short)f2bf(f.x);
        Bs[(c0 + h * 4 + 1) * 40 + kk] = (short)f2bf(f.y);
        Bs[(c0 + h * 4 + 2) * 40 + kk] = (short)f2bf(f.z);
        Bs[(c0 + h * 4 + 3) * 40 + kk] = (short)f2bf(f.w);
      }
    }
    __syncthreads();

    bf16x8 af[4], bfv[4];
#pragma unroll
    for (int i = 0; i < 4; ++i)
      af[i] = *(const bf16x8*)&As[(wm + i * 16 + l16) * 40 + quad * 8];
#pragma unroll
    for (int j = 0; j < 4; ++j)
      bfv[j] = *(const bf16x8*)&Bs[(wn + j * 16 + l16) * 40 + quad * 8];
#pragma unroll
    for (int i = 0; i < 4; ++i)
#pragma unroll
      for (int j = 0; j < 4; ++j)
        acc[i][j] = __builtin_amdgcn_mfma_f32_16x16x32_bf16(af[i], bfv[j],
                                                            acc[i][j], 0, 0, 0);
  }

  float* E = e + (size_t)b * TT * DD;
#pragma unroll
  for (int i = 0; i < 4; ++i)
#pragma unroll
    for (int j = 0; j < 4; ++j)
#pragma unroll
      for (int r = 0; r < 4; ++r) {
        const int row = m0 + wm + i * 16 + quad * 4 + r;
        const int col = n0 + wn + j * 16 + l16;
        E[(size_t)row * DD + col] = acc[i][j][r];
      }
}

// ---------------------------------------------------------------------------
extern "C" void kernel_launch(void* const* d_in, const int* in_sizes, int n_in,
                              void* d_out, int out_size, void* d_ws, size_t ws_size,
                              hipStream_t stream) {
  const float* ctx   = (const float*)d_in[0];   // [8,4096,1024] f32
  const float* query = (const float*)d_in[1];   // [8,512,1024]  f32
  const int*   mask  = (const int*)d_in[2];     // [8,4096]      int32

  float* expected = (float*)d_out;                              // [8,512,1024] f32
  float* p        = (float*)d_out + (size_t)BB * TT * DD;       // [8,512,4096] f32

  // 1) scores = Q C^T / 32 -> f32 into p region
  qk_kernel<<<dim3(SS / 128, TT / 128, BB), 256, 0, stream>>>(query, ctx, p);
  // 2) masked softmax in place (f32)
  softmax_kernel<<<dim3(BB * TT), 256, 0, stream>>>(p, mask);
  // 3) expected = P C -> f32
  pv_kernel<<<dim3(DD / 128, TT / 128, BB), 256, 0, stream>>>(p, ctx, expected);
}

// Round 5
// 447.304 us; speedup vs baseline: 1.1344x; 1.1344x over previous
//
#include <hip/hip_runtime.h>

// Problem dims (fixed by the reference)
#define BB 8
#define SS 4096
#define TT 512
#define DD 1024

typedef __attribute__((ext_vector_type(8))) short bf16x8;   // 8 bf16 = 16B
typedef __attribute__((ext_vector_type(4))) short bf16x4;   // 4 bf16 = 8B
typedef __attribute__((ext_vector_type(4))) float f32x4;

__device__ inline unsigned short f2bf(float f) {
  unsigned int u = __float_as_uint(f);
  u += 0x7FFFu + ((u >> 16) & 1u);   // round-to-nearest-even
  return (unsigned short)(u >> 16);
}
// pack 16 consecutive f32 -> two bf16x8 (16B-aligned dst)
__device__ inline void pack16(const float* __restrict__ src, short* __restrict__ dst) {
  f32x4 f0 = *(const f32x4*)(src + 0);
  f32x4 f1 = *(const f32x4*)(src + 4);
  f32x4 f2 = *(const f32x4*)(src + 8);
  f32x4 f3 = *(const f32x4*)(src + 12);
  bf16x8 b0, b1;
  b0[0] = (short)f2bf(f0.x); b0[1] = (short)f2bf(f0.y);
  b0[2] = (short)f2bf(f0.z); b0[3] = (short)f2bf(f0.w);
  b0[4] = (short)f2bf(f1.x); b0[5] = (short)f2bf(f1.y);
  b0[6] = (short)f2bf(f1.z); b0[7] = (short)f2bf(f1.w);
  b1[0] = (short)f2bf(f2.x); b1[1] = (short)f2bf(f2.y);
  b1[2] = (short)f2bf(f2.z); b1[3] = (short)f2bf(f2.w);
  b1[4] = (short)f2bf(f3.x); b1[5] = (short)f2bf(f3.y);
  b1[6] = (short)f2bf(f3.z); b1[7] = (short)f2bf(f3.w);
  *(bf16x8*)(dst + 0) = b0;
  *(bf16x8*)(dst + 8) = b1;
}

// ===========================================================================
// FAST PATH (needs 168 MB workspace)
// ws layout: q_bf16 [T,D] 8MB | c_bf16 [S,D] 64MB | cT_bf16 [D,S] 64MB |
//            p_bf16 [T,S] 32MB
// ===========================================================================
#define WS_NEED ((size_t)168 << 20)
#define OFF_QB  ((size_t)0)
#define OFF_CB  ((size_t)8 << 20)
#define OFF_CT  ((size_t)72 << 20)
#define OFF_PB  ((size_t)136 << 20)

// --- prep: query f32 -> bf16 (4M elems, 8/thread) ---------------------------
__global__ __launch_bounds__(256) void prep_q_kernel(const float* __restrict__ q,
                                                     short* __restrict__ qb) {
  const size_t idx = ((size_t)blockIdx.x * 256 + threadIdx.x) * 16;
  pack16(q + idx, qb + idx);
}

// --- prep: ctx f32 -> c_bf16 [S,D] AND cT_bf16 [D,S] (64x64 tiles) ----------
__global__ __launch_bounds__(256) void prep_c_kernel(const float* __restrict__ c,
                                                     short* __restrict__ cb,
                                                     short* __restrict__ ct) {
  const int b  = blockIdx.z;
  const int s0 = blockIdx.y * 64;
  const int d0 = blockIdx.x * 64;
  const float* C = c + (size_t)b * SS * DD;
  __shared__ float Tt[64][65];

  const int tid = threadIdx.x;
  // load 64x64 f32 tile, emit c_bf16 on the fly
#pragma unroll
  for (int h = 0; h < 4; ++h) {
    const int sl = (tid >> 4) + h * 16;
    const int dl = (tid & 15) * 4;
    f32x4 v = *(const f32x4*)(C + (size_t)(s0 + sl) * DD + d0 + dl);
    *(f32x4*)&Tt[sl][dl] = v;
    bf16x4 o;
    o[0] = (short)f2bf(v.x); o[1] = (short)f2bf(v.y);
    o[2] = (short)f2bf(v.z); o[3] = (short)f2bf(v.w);
    *(bf16x4*)(cb + (size_t)b * SS * DD + (size_t)(s0 + sl) * DD + d0 + dl) = o;
  }
  __syncthreads();
  // store transposed: cT[d][s]
#pragma unroll
  for (int g = 0; g < 2; ++g) {
    const int dl = (tid >> 3) + g * 32;
    const int sb = (tid & 7) * 8;
    bf16x8 o;
#pragma unroll
    for (int j = 0; j < 8; ++j) o[j] = (short)f2bf(Tt[sb + j][dl]);
    *(bf16x8*)(ct + (size_t)b * DD * SS + (size_t)(d0 + dl) * SS + s0 + sb) = o;
  }
}

// --- qk (bf16 NT GEMM) + fused mask -> f32 scores ---------------------------
__global__ __launch_bounds__(256) void qk_kernel_f(const short* __restrict__ qb,
                                                   const short* __restrict__ cb,
                                                   const int* __restrict__ mask,
                                                   float* __restrict__ p) {
  const int b  = blockIdx.z;
  const int m0 = blockIdx.y * 128;   // T
  const int n0 = blockIdx.x * 128;   // S
  const short* A  = qb + (size_t)b * TT * DD;
  const short* Bt = cb + (size_t)b * SS * DD;

  __shared__ alignas(16) short As[128 * 40];
  __shared__ alignas(16) short Bs[128 * 40];

  const int tid  = threadIdx.x;
  const int wave = tid >> 6, lane = tid & 63;
  const int quad = lane >> 4, l16 = lane & 15;
  const int wm = (wave >> 1) * 64, wn = (wave & 1) * 64;

  f32x4 acc[4][4];
#pragma unroll
  for (int i = 0; i < 4; ++i)
#pragma unroll
    for (int j = 0; j < 4; ++j) acc[i][j] = (f32x4){0.f, 0.f, 0.f, 0.f};

  const int ar = tid >> 1;
  const int ak = (tid & 1) * 16;

  for (int k0 = 0; k0 < DD; k0 += 32) {
    __syncthreads();
    {
      const short* ap = A  + (size_t)(m0 + ar) * DD + k0 + ak;
      const short* bp = Bt + (size_t)(n0 + ar) * DD + k0 + ak;
      *(bf16x8*)&As[ar * 40 + ak]     = *(const bf16x8*)(ap);
      *(bf16x8*)&As[ar * 40 + ak + 8] = *(const bf16x8*)(ap + 8);
      *(bf16x8*)&Bs[ar * 40 + ak]     = *(const bf16x8*)(bp);
      *(bf16x8*)&Bs[ar * 40 + ak + 8] = *(const bf16x8*)(bp + 8);
    }
    __syncthreads();

    bf16x8 af[4], bfv[4];
#pragma unroll
    for (int i = 0; i < 4; ++i)
      af[i] = *(const bf16x8*)&As[(wm + i * 16 + l16) * 40 + quad * 8];
#pragma unroll
    for (int j = 0; j < 4; ++j)
      bfv[j] = *(const bf16x8*)&Bs[(wn + j * 16 + l16) * 40 + quad * 8];
#pragma unroll
    for (int i = 0; i < 4; ++i)
#pragma unroll
      for (int j = 0; j < 4; ++j)
        acc[i][j] = __builtin_amdgcn_mfma_f32_16x16x32_bf16(af[i], bfv[j],
                                                            acc[i][j], 0, 0, 0);
  }

  // epilogue: scale + mask (masked cols -> -10000 so softmax needs no mask)
  float* P = p + (size_t)b * TT * SS;
  int mk[4];
#pragma unroll
  for (int j = 0; j < 4; ++j) mk[j] = mask[b * SS + n0 + wn + j * 16 + l16];
#pragma unroll
  for (int i = 0; i < 4; ++i)
#pragma unroll
    for (int j = 0; j < 4; ++j)
#pragma unroll
      for (int r = 0; r < 4; ++r) {
        const int row = m0 + wm + i * 16 + quad * 4 + r;
        const int col = n0 + wn + j * 16 + l16;
        const float val = (mk[j] == 0) ? -10000.0f : acc[i][j][r] * 0.03125f;
        P[(size_t)row * SS + col] = val;
      }
}

// --- softmax (f32 in-place) + bf16 copy for pv ------------------------------
__global__ __launch_bounds__(256) void softmax_kernel_f(float* __restrict__ p,
                                                        short* __restrict__ pb) {
  const int row = blockIdx.x;           // b*T + t
  float* pr = p + (size_t)row * SS;
  short* pbr = pb + (size_t)row * SS;
  const int tid = threadIdx.x;
  const int wave = tid >> 6, lane = tid & 63;

  float v[16];
  float mx = -3.0e38f;
#pragma unroll
  for (int h = 0; h < 4; ++h) {
    const int base = tid * 4 + h * 1024;
    f32x4 s = *(const f32x4*)(pr + base);
    v[h * 4 + 0] = s.x; v[h * 4 + 1] = s.y;
    v[h * 4 + 2] = s.z; v[h * 4 + 3] = s.w;
    mx = fmaxf(mx, fmaxf(fmaxf(s.x, s.y), fmaxf(s.z, s.w)));
  }
#pragma unroll
  for (int off = 32; off > 0; off >>= 1) mx = fmaxf(mx, __shfl_down(mx, off));
  __shared__ float red[4];
  if (lane == 0) red[wave] = mx;
  __syncthreads();
  mx = fmaxf(fmaxf(red[0], red[1]), fmaxf(red[2], red[3]));
  __syncthreads();

  float e[16];
  float sum = 0.f;
#pragma unroll
  for (int k = 0; k < 16; ++k) { e[k] = __expf(v[k] - mx); sum += e[k]; }
#pragma unroll
  for (int off = 32; off > 0; off >>= 1) sum += __shfl_down(sum, off);
  if (lane == 0) red[wave] = sum;
  __syncthreads();
  const float inv = 1.0f / (red[0] + red[1] + red[2] + red[3]);

#pragma unroll
  for (int h = 0; h < 4; ++h) {
    const int base = tid * 4 + h * 1024;
    f32x4 o;
    o.x = e[h * 4 + 0] * inv; o.y = e[h * 4 + 1] * inv;
    o.z = e[h * 4 + 2] * inv; o.w = e[h * 4 + 3] * inv;
    *(f32x4*)(pr + base) = o;
    bf16x4 ob;
    ob[0] = (short)f2bf(o.x); ob[1] = (short)f2bf(o.y);
    ob[2] = (short)f2bf(o.z); ob[3] = (short)f2bf(o.w);
    *(bf16x4*)(pbr + base) = ob;
  }
}

// --- pv (bf16 NT GEMM, split-K=4, atomicAdd f32 epilogue) -------------------
__global__ __launch_bounds__(256) void pv_kernel_f(const short* __restrict__ pb,
                                                   const short* __restrict__ ct,
                                                   float* __restrict__ e) {
  const int b  = blockIdx.z >> 2;
  const int ks = blockIdx.z & 3;     // K slice: s in [ks*1024, ks*1024+1024)
  const int m0 = blockIdx.y * 128;   // T
  const int n0 = blockIdx.x * 128;   // D
  const short* A  = pb + (size_t)b * TT * SS;
  const short* Bt = ct + (size_t)b * DD * SS;

  __shared__ alignas(16) short As[128 * 40];
  __shared__ alignas(16) short Bs[128 * 40];

  const int tid  = threadIdx.x;
  const int wave = tid >> 6, lane = tid & 63;
  const int quad = lane >> 4, l16 = lane & 15;
  const int wm = (wave >> 1) * 64, wn = (wave & 1) * 64;

  f32x4 acc[4][4];
#pragma unroll
  for (int i = 0; i < 4; ++i)
#pragma unroll
    for (int j = 0; j < 4; ++j) acc[i][j] = (f32x4){0.f, 0.f, 0.f, 0.f};

  const int ar = tid >> 1;
  const int ak = (tid & 1) * 16;
  const int kend = ks * 1024 + 1024;

  for (int k0 = ks * 1024; k0 < kend; k0 += 32) {
    __syncthreads();
    {
      const short* ap = A  + (size_t)(m0 + ar) * SS + k0 + ak;
      const short* bp = Bt + (size_t)(n0 + ar) * SS + k0 + ak;
      *(bf16x8*)&As[ar * 40 + ak]     = *(const bf16x8*)(ap);
      *(bf16x8*)&As[ar * 40 + ak + 8] = *(const bf16x8*)(ap + 8);
      *(bf16x8*)&Bs[ar * 40 + ak]     = *(const bf16x8*)(bp);
      *(bf16x8*)&Bs[ar * 40 + ak + 8] = *(const bf16x8*)(bp + 8);
    }
    __syncthreads();

    bf16x8 af[4], bfv[4];
#pragma unroll
    for (int i = 0; i < 4; ++i)
      af[i] = *(const bf16x8*)&As[(wm + i * 16 + l16) * 40 + quad * 8];
#pragma unroll
    for (int j = 0; j < 4; ++j)
      bfv[j] = *(const bf16x8*)&Bs[(wn + j * 16 + l16) * 40 + quad * 8];
#pragma unroll
    for (int i = 0; i < 4; ++i)
#pragma unroll
      for (int j = 0; j < 4; ++j)
        acc[i][j] = __builtin_amdgcn_mfma_f32_16x16x32_bf16(af[i], bfv[j],
                                                            acc[i][j], 0, 0, 0);
  }

  float* E = e + (size_t)b * TT * DD;
#pragma unroll
  for (int i = 0; i < 4; ++i)
#pragma unroll
    for (int j = 0; j < 4; ++j)
#pragma unroll
      for (int r = 0; r < 4; ++r) {
        const int row = m0 + wm + i * 16 + quad * 4 + r;
        const int col = n0 + wn + j * 16 + l16;
        atomicAdd(&E[(size_t)row * DD + col], acc[i][j][r]);
      }
}

// ===========================================================================
// FALLBACK PATH (R4 kernels, used when ws_size < WS_NEED)
// ===========================================================================
__global__ __launch_bounds__(256) void qk_kernel(const float* __restrict__ q,
                                                 const float* __restrict__ c,
                                                 float* __restrict__ p) {
  const int b  = blockIdx.z;
  const int m0 = blockIdx.y * 128;
  const int n0 = blockIdx.x * 128;
  const float* A  = q + (size_t)b * TT * DD;
  const float* Bt = c + (size_t)b * SS * DD;
  __shared__ alignas(16) short As[128 * 40];
  __shared__ alignas(16) short Bs[128 * 40];
  const int tid  = threadIdx.x;
  const int wave = tid >> 6, lane = tid & 63;
  const int quad = lane >> 4, l16 = lane & 15;
  const int wm = (wave >> 1) * 64, wn = (wave & 1) * 64;
  f32x4 acc[4][4];
#pragma unroll
  for (int i = 0; i < 4; ++i)
#pragma unroll
    for (int j = 0; j < 4; ++j) acc[i][j] = (f32x4){0.f, 0.f, 0.f, 0.f};
  const int ar = tid >> 1;
  const int ak = (tid & 1) * 16;
  for (int k0 = 0; k0 < DD; k0 += 32) {
    __syncthreads();
    pack16(A  + (size_t)(m0 + ar) * DD + k0 + ak, &As[ar * 40 + ak]);
    pack16(Bt + (size_t)(n0 + ar) * DD + k0 + ak, &Bs[ar * 40 + ak]);
    __syncthreads();
    bf16x8 af[4], bfv[4];
#pragma unroll
    for (int i = 0; i < 4; ++i)
      af[i] = *(const bf16x8*)&As[(wm + i * 16 + l16) * 40 + quad * 8];
#pragma unroll
    for (int j = 0; j < 4; ++j)
      bfv[j] = *(const bf16x8*)&Bs[(wn + j * 16 + l16) * 40 + quad * 8];
#pragma unroll
    for (int i = 0; i < 4; ++i)
#pragma unroll
      for (int j = 0; j < 4; ++j)
        acc[i][j] = __builtin_amdgcn_mfma_f32_16x16x32_bf16(af[i], bfv[j],
                                                            acc[i][j], 0, 0, 0);
  }
  float* P = p + (size_t)b * TT * SS;
#pragma unroll
  for (int i = 0; i < 4; ++i)
#pragma unroll
    for (int j = 0; j < 4; ++j)
#pragma unroll
      for (int r = 0; r < 4; ++r) {
        const int row = m0 + wm + i * 16 + quad * 4 + r;
        const int col = n0 + wn + j * 16 + l16;
        P[(size_t)row * SS + col] = acc[i][j][r] * 0.03125f;
      }
}

__global__ __launch_bounds__(256) void softmax_kernel(float* __restrict__ p,
                                                      const int* __restrict__ mask) {
  const int row = blockIdx.x;
  const int b   = row >> 9;
  float* pr = p + (size_t)row * SS;
  const int* mr = mask + b * SS;
  const int tid = threadIdx.x;
  const int wave = tid >> 6, lane = tid & 63;
  float v[16];
  float mx = -3.0e38f;
#pragma unroll
  for (int h = 0; h < 4; ++h) {
    const int base = tid * 4 + h * 1024;
    f32x4 s = *(const f32x4*)(pr + base);
    const int4 m4 = *(const int4*)(mr + base);
#pragma unroll
    for (int j = 0; j < 4; ++j) {
      float f = (j == 0 ? s.x : j == 1 ? s.y : j == 2 ? s.z : s.w);
      const int mk = (j == 0 ? m4.x : j == 1 ? m4.y : j == 2 ? m4.z : m4.w);
      f = fminf(fmaxf(f, -1.0e30f), 1.0e30f);
      f = (mk == 0) ? -10000.0f : f;
      v[h * 4 + j] = f;
      mx = fmaxf(mx, f);
    }
  }
#pragma unroll
  for (int off = 32; off > 0; off >>= 1) mx = fmaxf(mx, __shfl_down(mx, off));
  __shared__ float red[4];
  if (lane == 0) red[wave] = mx;
  __syncthreads();
  mx = fmaxf(fmaxf(red[0], red[1]), fmaxf(red[2], red[3]));
  __syncthreads();
  float e[16];
  float sum = 0.f;
#pragma unroll
  for (int k = 0; k < 16; ++k) { e[k] = __expf(v[k] - mx); sum += e[k]; }
#pragma unroll
  for (int off = 32; off > 0; off >>= 1) sum += __shfl_down(sum, off);
  if (lane == 0) red[wave] = sum;
  __syncthreads();
  const float inv = 1.0f / (red[0] + red[1] + red[2] + red[3]);
#pragma unroll
  for (int h = 0; h < 4; ++h) {
    const int base = tid * 4 + h * 1024;
    f32x4 o;
    o.x = e[h * 4 + 0] * inv; o.y = e[h * 4 + 1] * inv;
    o.z = e[h * 4 + 2] * inv; o.w = e[h * 4 + 3] * inv;
    *(f32x4*)(pr + base) = o;
  }
}

__global__ __launch_bounds__(256) void pv_kernel(const float* __restrict__ p,
                                                 const float* __restrict__ c,
                                                 float* __restrict__ e) {
  const int b  = blockIdx.z;
  const int m0 = blockIdx.y * 128;
  const int n0 = blockIdx.x * 128;
  const float* A  = p + (size_t)b * TT * SS;
  const float* Bm = c + (size_t)b * SS * DD;
  __shared__ alignas(16) short As[128 * 40];
  __shared__ alignas(16) short Bs[128 * 40];
  const int tid  = threadIdx.x;
  const int wave = tid >> 6, lane = tid & 63;
  const int quad = lane >> 4, l16 = lane & 15;
  const int wm = (wave >> 1) * 64, wn = (wave & 1) * 64;
  f32x4 acc[4][4];
#pragma unroll
  for (int i = 0; i < 4; ++i)
#pragma unroll
    for (int j = 0; j < 4; ++j) acc[i][j] = (f32x4){0.f, 0.f, 0.f, 0.f};
  const int ar = tid >> 1;
  const int ak = (tid & 1) * 16;
  const int kk = tid >> 3;
  const int c0 = (tid & 7) * 16;
  for (int k0 = 0; k0 < SS; k0 += 32) {
    __syncthreads();
    pack16(A + (size_t)(m0 + ar) * SS + k0 + ak, &As[ar * 40 + ak]);
    {
      const float* bp = Bm + (size_t)(k0 + kk) * DD + n0 + c0;
#pragma unroll
      for (int h = 0; h < 4; ++h) {
        f32x4 f = *(const f32x4*)(bp + h * 4);
        Bs[(c0 + h * 4 + 0) * 40 + kk] = (short)f2bf(f.x);
        Bs[(c0 + h * 4 + 1) * 40 + kk] = (short)f2bf(f.y);
        Bs[(c0 + h * 4 + 2) * 40 + kk] = (short)f2bf(f.z);
        Bs[(c0 + h * 4 + 3) * 40 + kk] = (short)f2bf(f.w);
      }
    }
    __syncthreads();
    bf16x8 af[4], bfv[4];
#pragma unroll
    for (int i = 0; i < 4; ++i)
      af[i] = *(const bf16x8*)&As[(wm + i * 16 + l16) * 40 + quad * 8];
#pragma unroll
    for (int j = 0; j < 4; ++j)
      bfv[j] = *(const bf16x8*)&Bs[(wn + j * 16 + l16) * 40 + quad * 8];
#pragma unroll
    for (int i = 0; i < 4; ++i)
#pragma unroll
      for (int j = 0; j < 4; ++j)
        acc[i][j] = __builtin_amdgcn_mfma_f32_16x16x32_bf16(af[i], bfv[j],
                                                            acc[i][j], 0, 0, 0);
  }
  float* E = e + (size_t)b * TT * DD;
#pragma unroll
  for (int i = 0; i < 4; ++i)
#pragma unroll
    for (int j = 0; j < 4; ++j)
#pragma unroll
      for (int r = 0; r < 4; ++r) {
        const int row = m0 + wm + i * 16 + quad * 4 + r;
        const int col = n0 + wn + j * 16 + l16;
        E[(size_t)row * DD + col] = acc[i][j][r];
      }
}

// ---------------------------------------------------------------------------
extern "C" void kernel_launch(void* const* d_in, const int* in_sizes, int n_in,
                              void* d_out, int out_size, void* d_ws, size_t ws_size,
                              hipStream_t stream) {
  const float* ctx   = (const float*)d_in[0];   // [8,4096,1024] f32
  const float* query = (const float*)d_in[1];   // [8,512,1024]  f32
  const int*   mask  = (const int*)d_in[2];     // [8,4096]      int32

  float* expected = (float*)d_out;                              // [8,512,1024] f32
  float* p        = (float*)d_out + (size_t)BB * TT * DD;       // [8,512,4096] f32

  if (ws_size >= WS_NEED) {
    char* ws = (char*)d_ws;
    short* qb = (short*)(ws + OFF_QB);
    short* cb = (short*)(ws + OFF_CB);
    short* ct = (short*)(ws + OFF_CT);
    short* pb = (short*)(ws + OFF_PB);

    prep_q_kernel<<<dim3((BB * TT * DD) / (256 * 16)), 256, 0, stream>>>(query, qb);
    prep_c_kernel<<<dim3(DD / 64, SS / 64, BB), 256, 0, stream>>>(ctx, cb, ct);
    qk_kernel_f<<<dim3(SS / 128, TT / 128, BB), 256, 0, stream>>>(qb, cb, mask, p);
    softmax_kernel_f<<<dim3(BB * TT), 256, 0, stream>>>(p, pb);
    hipMemsetAsync(expected, 0, (size_t)BB * TT * DD * sizeof(float), stream);
    pv_kernel_f<<<dim3(DD / 128, TT / 128, BB * 4), 256, 0, stream>>>(pb, ct, expected);
  } else {
    // fallback: R4 proven path
    qk_kernel<<<dim3(SS / 128, TT / 128, BB), 256, 0, stream>>>(query, ctx, p);
    softmax_kernel<<<dim3(BB * TT), 256, 0, stream>>>(p, mask);
    pv_kernel<<<dim3(DD / 128, TT / 128, BB), 256, 0, stream>>>(p, ctx, expected);
  }
}

// Round 6
// 447.079 us; speedup vs baseline: 1.1350x; 1.0005x over previous
//
#include <hip/hip_runtime.h>

// Problem dims (fixed by the reference)
#define BB 8
#define SS 4096
#define TT 512
#define DD 1024

typedef __attribute__((ext_vector_type(8))) short bf16x8;   // 8 bf16 = 16B
typedef __attribute__((ext_vector_type(4))) short bf16x4;   // 4 bf16 = 8B
typedef __attribute__((ext_vector_type(4))) float f32x4;

// async global->LDS, 16B per lane; LDS dest = wave-uniform base + lane*16
#define GLOAD_LDS16(gp, lp)                                            \
  __builtin_amdgcn_global_load_lds(                                    \
      (const __attribute__((address_space(1))) void*)(gp),             \
      (__attribute__((address_space(3))) void*)(lp), 16, 0, 0)

__device__ inline unsigned short f2bf(float f) {
  unsigned int u = __float_as_uint(f);
  u += 0x7FFFu + ((u >> 16) & 1u);   // round-to-nearest-even
  return (unsigned short)(u >> 16);
}
// pack 16 consecutive f32 -> two bf16x8 (16B-aligned dst)
__device__ inline void pack16(const float* __restrict__ src, short* __restrict__ dst) {
  f32x4 f0 = *(const f32x4*)(src + 0);
  f32x4 f1 = *(const f32x4*)(src + 4);
  f32x4 f2 = *(const f32x4*)(src + 8);
  f32x4 f3 = *(const f32x4*)(src + 12);
  bf16x8 b0, b1;
  b0[0] = (short)f2bf(f0.x); b0[1] = (short)f2bf(f0.y);
  b0[2] = (short)f2bf(f0.z); b0[3] = (short)f2bf(f0.w);
  b0[4] = (short)f2bf(f1.x); b0[5] = (short)f2bf(f1.y);
  b0[6] = (short)f2bf(f1.z); b0[7] = (short)f2bf(f1.w);
  b1[0] = (short)f2bf(f2.x); b1[1] = (short)f2bf(f2.y);
  b1[2] = (short)f2bf(f2.z); b1[3] = (short)f2bf(f2.w);
  b1[4] = (short)f2bf(f3.x); b1[5] = (short)f2bf(f3.y);
  b1[6] = (short)f2bf(f3.z); b1[7] = (short)f2bf(f3.w);
  *(bf16x8*)(dst + 0) = b0;
  *(bf16x8*)(dst + 8) = b1;
}

// ===========================================================================
// FAST PATH (needs 168 MB workspace)
// ws: q_bf16 [T,D] 8MB | c_bf16 [S,D] 64MB | cT_bf16 [D,S] 64MB | p_bf16 32MB
// ===========================================================================
#define WS_NEED ((size_t)168 << 20)
#define OFF_QB  ((size_t)0)
#define OFF_CB  ((size_t)8 << 20)
#define OFF_CT  ((size_t)72 << 20)
#define OFF_PB  ((size_t)136 << 20)

// --- prep: query f32 -> bf16 ------------------------------------------------
__global__ __launch_bounds__(256) void prep_q_kernel(const float* __restrict__ q,
                                                     short* __restrict__ qb) {
  const size_t idx = ((size_t)blockIdx.x * 256 + threadIdx.x) * 16;
  pack16(q + idx, qb + idx);
}

// --- prep: ctx f32 -> c_bf16 [S,D] AND cT_bf16 [D,S] (64x64 tiles) ----------
__global__ __launch_bounds__(256) void prep_c_kernel(const float* __restrict__ c,
                                                     short* __restrict__ cb,
                                                     short* __restrict__ ct) {
  const int b  = blockIdx.z;
  const int s0 = blockIdx.y * 64;
  const int d0 = blockIdx.x * 64;
  const float* C = c + (size_t)b * SS * DD;
  __shared__ float Tt[64][65];

  const int tid = threadIdx.x;
#pragma unroll
  for (int h = 0; h < 4; ++h) {
    const int sl = (tid >> 4) + h * 16;
    const int dl = (tid & 15) * 4;
    f32x4 v = *(const f32x4*)(C + (size_t)(s0 + sl) * DD + d0 + dl);
    *(f32x4*)&Tt[sl][dl] = v;
    bf16x4 o;
    o[0] = (short)f2bf(v.x); o[1] = (short)f2bf(v.y);
    o[2] = (short)f2bf(v.z); o[3] = (short)f2bf(v.w);
    *(bf16x4*)(cb + (size_t)b * SS * DD + (size_t)(s0 + sl) * DD + d0 + dl) = o;
  }
  __syncthreads();
#pragma unroll
  for (int g = 0; g < 2; ++g) {
    const int dl = (tid >> 3) + g * 32;
    const int sb = (tid & 7) * 8;
    bf16x8 o;
#pragma unroll
    for (int j = 0; j < 8; ++j) o[j] = (short)f2bf(Tt[sb + j][dl]);
    *(bf16x8*)(ct + (size_t)b * DD * SS + (size_t)(d0 + dl) * SS + s0 + sb) = o;
  }
}

// ---------------------------------------------------------------------------
// Shared GEMM core macro pieces (qk / pv): 128x128 tile, BK=32,
// global_load_lds width-16 staging, unpadded LDS [128][32] (row = 64B).
// Chunk swizzle: lane loads global chunk (lane&3)^((lane>>3)&3); fragment
// read slot = quad ^ ((l16>>1)&3)  (lane-constant) -> uniform bank groups.
// ---------------------------------------------------------------------------

// --- qk (bf16 NT GEMM, async staging) + fused mask -> f32 scores ------------
__global__ __launch_bounds__(256) void qk_kernel_f(const short* __restrict__ qb,
                                                   const short* __restrict__ cb,
                                                   const int* __restrict__ mask,
                                                   float* __restrict__ p) {
  const int b  = blockIdx.z;
  const int m0 = blockIdx.y * 128;   // T
  const int n0 = blockIdx.x * 128;   // S
  const short* A  = qb + (size_t)b * TT * DD;
  const short* Bt = cb + (size_t)b * SS * DD;

  __shared__ alignas(16) short As[128 * 32];
  __shared__ alignas(16) short Bs[128 * 32];

  const int tid  = threadIdx.x;
  const int wave = tid >> 6, lane = tid & 63;
  const int quad = lane >> 4, l16 = lane & 15;
  const int wm = (wave >> 1) * 64, wn = (wave & 1) * 64;

  const int rl = lane >> 2;                          // staging row 0..15
  const int ck = (lane & 3) ^ ((lane >> 3) & 3);     // swizzled k-chunk
  const int slot = (quad ^ ((l16 >> 1) & 3)) * 8;    // read-side slot (shorts)

  f32x4 acc[4][4];
#pragma unroll
  for (int i = 0; i < 4; ++i)
#pragma unroll
    for (int j = 0; j < 4; ++j) acc[i][j] = (f32x4){0.f, 0.f, 0.f, 0.f};

  for (int k0 = 0; k0 < DD; k0 += 32) {
    __syncthreads();
#pragma unroll
    for (int t = 0; t < 2; ++t) {
      const int rb = wave * 32 + t * 16;             // wave-uniform row base
      GLOAD_LDS16(A  + (size_t)(m0 + rb + rl) * DD + k0 + ck * 8, &As[rb * 32]);
      GLOAD_LDS16(Bt + (size_t)(n0 + rb + rl) * DD + k0 + ck * 8, &Bs[rb * 32]);
    }
    __syncthreads();

    bf16x8 af[4], bfv[4];
#pragma unroll
    for (int i = 0; i < 4; ++i)
      af[i] = *(const bf16x8*)&As[(wm + i * 16 + l16) * 32 + slot];
#pragma unroll
    for (int j = 0; j < 4; ++j)
      bfv[j] = *(const bf16x8*)&Bs[(wn + j * 16 + l16) * 32 + slot];
#pragma unroll
    for (int i = 0; i < 4; ++i)
#pragma unroll
      for (int j = 0; j < 4; ++j)
        acc[i][j] = __builtin_amdgcn_mfma_f32_16x16x32_bf16(af[i], bfv[j],
                                                            acc[i][j], 0, 0, 0);
  }

  // epilogue: scale + mask (masked cols -> -10000; softmax needs no mask)
  float* P = p + (size_t)b * TT * SS;
  int mk[4];
#pragma unroll
  for (int j = 0; j < 4; ++j) mk[j] = mask[b * SS + n0 + wn + j * 16 + l16];
#pragma unroll
  for (int i = 0; i < 4; ++i)
#pragma unroll
    for (int j = 0; j < 4; ++j)
#pragma unroll
      for (int r = 0; r < 4; ++r) {
        const int row = m0 + wm + i * 16 + quad * 4 + r;
        const int col = n0 + wn + j * 16 + l16;
        const float val = (mk[j] == 0) ? -10000.0f : acc[i][j][r] * 0.03125f;
        P[(size_t)row * SS + col] = val;
      }
}

// --- softmax (f32 in-place) + bf16 copy for pv ------------------------------
__global__ __launch_bounds__(256) void softmax_kernel_f(float* __restrict__ p,
                                                        short* __restrict__ pb) {
  const int row = blockIdx.x;           // b*T + t
  float* pr = p + (size_t)row * SS;
  short* pbr = pb + (size_t)row * SS;
  const int tid = threadIdx.x;
  const int wave = tid >> 6, lane = tid & 63;

  float v[16];
  float mx = -3.0e38f;
#pragma unroll
  for (int h = 0; h < 4; ++h) {
    const int base = tid * 4 + h * 1024;
    f32x4 s = *(const f32x4*)(pr + base);
    v[h * 4 + 0] = s.x; v[h * 4 + 1] = s.y;
    v[h * 4 + 2] = s.z; v[h * 4 + 3] = s.w;
    mx = fmaxf(mx, fmaxf(fmaxf(s.x, s.y), fmaxf(s.z, s.w)));
  }
#pragma unroll
  for (int off = 32; off > 0; off >>= 1) mx = fmaxf(mx, __shfl_down(mx, off));
  __shared__ float red[4];
  if (lane == 0) red[wave] = mx;
  __syncthreads();
  mx = fmaxf(fmaxf(red[0], red[1]), fmaxf(red[2], red[3]));
  __syncthreads();

  float e[16];
  float sum = 0.f;
#pragma unroll
  for (int k = 0; k < 16; ++k) { e[k] = __expf(v[k] - mx); sum += e[k]; }
#pragma unroll
  for (int off = 32; off > 0; off >>= 1) sum += __shfl_down(sum, off);
  if (lane == 0) red[wave] = sum;
  __syncthreads();
  const float inv = 1.0f / (red[0] + red[1] + red[2] + red[3]);

#pragma unroll
  for (int h = 0; h < 4; ++h) {
    const int base = tid * 4 + h * 1024;
    f32x4 o;
    o.x = e[h * 4 + 0] * inv; o.y = e[h * 4 + 1] * inv;
    o.z = e[h * 4 + 2] * inv; o.w = e[h * 4 + 3] * inv;
    *(f32x4*)(pr + base) = o;
    bf16x4 ob;
    ob[0] = (short)f2bf(o.x); ob[1] = (short)f2bf(o.y);
    ob[2] = (short)f2bf(o.z); ob[3] = (short)f2bf(o.w);
    *(bf16x4*)(pbr + base) = ob;
  }
}

// --- pv (bf16 NT GEMM, async staging, split-K=4, atomicAdd epilogue) --------
__global__ __launch_bounds__(256) void pv_kernel_f(const short* __restrict__ pb,
                                                   const short* __restrict__ ct,
                                                   float* __restrict__ e) {
  const int b  = blockIdx.z >> 2;
  const int ks = blockIdx.z & 3;     // K slice: s in [ks*1024, +1024)
  const int m0 = blockIdx.y * 128;   // T
  const int n0 = blockIdx.x * 128;   // D
  const short* A  = pb + (size_t)b * TT * SS;
  const short* Bt = ct + (size_t)b * DD * SS;

  __shared__ alignas(16) short As[128 * 32];
  __shared__ alignas(16) short Bs[128 * 32];

  const int tid  = threadIdx.x;
  const int wave = tid >> 6, lane = tid & 63;
  const int quad = lane >> 4, l16 = lane & 15;
  const int wm = (wave >> 1) * 64, wn = (wave & 1) * 64;

  const int rl = lane >> 2;
  const int ck = (lane & 3) ^ ((lane >> 3) & 3);
  const int slot = (quad ^ ((l16 >> 1) & 3)) * 8;

  f32x4 acc[4][4];
#pragma unroll
  for (int i = 0; i < 4; ++i)
#pragma unroll
    for (int j = 0; j < 4; ++j) acc[i][j] = (f32x4){0.f, 0.f, 0.f, 0.f};

  const int kend = ks * 1024 + 1024;
  for (int k0 = ks * 1024; k0 < kend; k0 += 32) {
    __syncthreads();
#pragma unroll
    for (int t = 0; t < 2; ++t) {
      const int rb = wave * 32 + t * 16;
      GLOAD_LDS16(A  + (size_t)(m0 + rb + rl) * SS + k0 + ck * 8, &As[rb * 32]);
      GLOAD_LDS16(Bt + (size_t)(n0 + rb + rl) * SS + k0 + ck * 8, &Bs[rb * 32]);
    }
    __syncthreads();

    bf16x8 af[4], bfv[4];
#pragma unroll
    for (int i = 0; i < 4; ++i)
      af[i] = *(const bf16x8*)&As[(wm + i * 16 + l16) * 32 + slot];
#pragma unroll
    for (int j = 0; j < 4; ++j)
      bfv[j] = *(const bf16x8*)&Bs[(wn + j * 16 + l16) * 32 + slot];
#pragma unroll
    for (int i = 0; i < 4; ++i)
#pragma unroll
      for (int j = 0; j < 4; ++j)
        acc[i][j] = __builtin_amdgcn_mfma_f32_16x16x32_bf16(af[i], bfv[j],
                                                            acc[i][j], 0, 0, 0);
  }

  float* E = e + (size_t)b * TT * DD;
#pragma unroll
  for (int i = 0; i < 4; ++i)
#pragma unroll
    for (int j = 0; j < 4; ++j)
#pragma unroll
      for (int r = 0; r < 4; ++r) {
        const int row = m0 + wm + i * 16 + quad * 4 + r;
        const int col = n0 + wn + j * 16 + l16;
        atomicAdd(&E[(size_t)row * DD + col], acc[i][j][r]);
      }
}

// ===========================================================================
// FALLBACK PATH (R4 kernels, used when ws_size < WS_NEED)
// ===========================================================================
__global__ __launch_bounds__(256) void qk_kernel(const float* __restrict__ q,
                                                 const float* __restrict__ c,
                                                 float* __restrict__ p) {
  const int b  = blockIdx.z;
  const int m0 = blockIdx.y * 128;
  const int n0 = blockIdx.x * 128;
  const float* A  = q + (size_t)b * TT * DD;
  const float* Bt = c + (size_t)b * SS * DD;
  __shared__ alignas(16) short As[128 * 40];
  __shared__ alignas(16) short Bs[128 * 40];
  const int tid  = threadIdx.x;
  const int wave = tid >> 6, lane = tid & 63;
  const int quad = lane >> 4, l16 = lane & 15;
  const int wm = (wave >> 1) * 64, wn = (wave & 1) * 64;
  f32x4 acc[4][4];
#pragma unroll
  for (int i = 0; i < 4; ++i)
#pragma unroll
    for (int j = 0; j < 4; ++j) acc[i][j] = (f32x4){0.f, 0.f, 0.f, 0.f};
  const int ar = tid >> 1;
  const int ak = (tid & 1) * 16;
  for (int k0 = 0; k0 < DD; k0 += 32) {
    __syncthreads();
    pack16(A  + (size_t)(m0 + ar) * DD + k0 + ak, &As[ar * 40 + ak]);
    pack16(Bt + (size_t)(n0 + ar) * DD + k0 + ak, &Bs[ar * 40 + ak]);
    __syncthreads();
    bf16x8 af[4], bfv[4];
#pragma unroll
    for (int i = 0; i < 4; ++i)
      af[i] = *(const bf16x8*)&As[(wm + i * 16 + l16) * 40 + quad * 8];
#pragma unroll
    for (int j = 0; j < 4; ++j)
      bfv[j] = *(const bf16x8*)&Bs[(wn + j * 16 + l16) * 40 + quad * 8];
#pragma unroll
    for (int i = 0; i < 4; ++i)
#pragma unroll
      for (int j = 0; j < 4; ++j)
        acc[i][j] = __builtin_amdgcn_mfma_f32_16x16x32_bf16(af[i], bfv[j],
                                                            acc[i][j], 0, 0, 0);
  }
  float* P = p + (size_t)b * TT * SS;
#pragma unroll
  for (int i = 0; i < 4; ++i)
#pragma unroll
    for (int j = 0; j < 4; ++j)
#pragma unroll
      for (int r = 0; r < 4; ++r) {
        const int row = m0 + wm + i * 16 + quad * 4 + r;
        const int col = n0 + wn + j * 16 + l16;
        P[(size_t)row * SS + col] = acc[i][j][r] * 0.03125f;
      }
}

__global__ __launch_bounds__(256) void softmax_kernel(float* __restrict__ p,
                                                      const int* __restrict__ mask) {
  const int row = blockIdx.x;
  const int b   = row >> 9;
  float* pr = p + (size_t)row * SS;
  const int* mr = mask + b * SS;
  const int tid = threadIdx.x;
  const int wave = tid >> 6, lane = tid & 63;
  float v[16];
  float mx = -3.0e38f;
#pragma unroll
  for (int h = 0; h < 4; ++h) {
    const int base = tid * 4 + h * 1024;
    f32x4 s = *(const f32x4*)(pr + base);
    const int4 m4 = *(const int4*)(mr + base);
#pragma unroll
    for (int j = 0; j < 4; ++j) {
      float f = (j == 0 ? s.x : j == 1 ? s.y : j == 2 ? s.z : s.w);
      const int mk = (j == 0 ? m4.x : j == 1 ? m4.y : j == 2 ? m4.z : m4.w);
      f = fminf(fmaxf(f, -1.0e30f), 1.0e30f);
      f = (mk == 0) ? -10000.0f : f;
      v[h * 4 + j] = f;
      mx = fmaxf(mx, f);
    }
  }
#pragma unroll
  for (int off = 32; off > 0; off >>= 1) mx = fmaxf(mx, __shfl_down(mx, off));
  __shared__ float red[4];
  if (lane == 0) red[wave] = mx;
  __syncthreads();
  mx = fmaxf(fmaxf(red[0], red[1]), fmaxf(red[2], red[3]));
  __syncthreads();
  float e[16];
  float sum = 0.f;
#pragma unroll
  for (int k = 0; k < 16; ++k) { e[k] = __expf(v[k] - mx); sum += e[k]; }
#pragma unroll
  for (int off = 32; off > 0; off >>= 1) sum += __shfl_down(sum, off);
  if (lane == 0) red[wave] = sum;
  __syncthreads();
  const float inv = 1.0f / (red[0] + red[1] + red[2] + red[3]);
#pragma unroll
  for (int h = 0; h < 4; ++h) {
    const int base = tid * 4 + h * 1024;
    f32x4 o;
    o.x = e[h * 4 + 0] * inv; o.y = e[h * 4 + 1] * inv;
    o.z = e[h * 4 + 2] * inv; o.w = e[h * 4 + 3] * inv;
    *(f32x4*)(pr + base) = o;
  }
}

__global__ __launch_bounds__(256) void pv_kernel(const float* __restrict__ p,
                                                 const float* __restrict__ c,
                                                 float* __restrict__ e) {
  const int b  = blockIdx.z;
  const int m0 = blockIdx.y * 128;
  const int n0 = blockIdx.x * 128;
  const float* A  = p + (size_t)b * TT * SS;
  const float* Bm = c + (size_t)b * SS * DD;
  __shared__ alignas(16) short As[128 * 40];
  __shared__ alignas(16) short Bs[128 * 40];
  const int tid  = threadIdx.x;
  const int wave = tid >> 6, lane = tid & 63;
  const int quad = lane >> 4, l16 = lane & 15;
  const int wm = (wave >> 1) * 64, wn = (wave & 1) * 64;
  f32x4 acc[4][4];
#pragma unroll
  for (int i = 0; i < 4; ++i)
#pragma unroll
    for (int j = 0; j < 4; ++j) acc[i][j] = (f32x4){0.f, 0.f, 0.f, 0.f};
  const int ar = tid >> 1;
  const int ak = (tid & 1) * 16;
  const int kk = tid >> 3;
  const int c0 = (tid & 7) * 16;
  for (int k0 = 0; k0 < SS; k0 += 32) {
    __syncthreads();
    pack16(A + (size_t)(m0 + ar) * SS + k0 + ak, &As[ar * 40 + ak]);
    {
      const float* bp = Bm + (size_t)(k0 + kk) * DD + n0 + c0;
#pragma unroll
      for (int h = 0; h < 4; ++h) {
        f32x4 f = *(const f32x4*)(bp + h * 4);
        Bs[(c0 + h * 4 + 0) * 40 + kk] = (short)f2bf(f.x);
        Bs[(c0 + h * 4 + 1) * 40 + kk] = (short)f2bf(f.y);
        Bs[(c0 + h * 4 + 2) * 40 + kk] = (short)f2bf(f.z);
        Bs[(c0 + h * 4 + 3) * 40 + kk] = (short)f2bf(f.w);
      }
    }
    __syncthreads();
    bf16x8 af[4], bfv[4];
#pragma unroll
    for (int i = 0; i < 4; ++i)
      af[i] = *(const bf16x8*)&As[(wm + i * 16 + l16) * 40 + quad * 8];
#pragma unroll
    for (int j = 0; j < 4; ++j)
      bfv[j] = *(const bf16x8*)&Bs[(wn + j * 16 + l16) * 40 + quad * 8];
#pragma unroll
    for (int i = 0; i < 4; ++i)
#pragma unroll
      for (int j = 0; j < 4; ++j)
        acc[i][j] = __builtin_amdgcn_mfma_f32_16x16x32_bf16(af[i], bfv[j],
                                                            acc[i][j], 0, 0, 0);
  }
  float* E = e + (size_t)b * TT * DD;
#pragma unroll
  for (int i = 0; i < 4; ++i)
#pragma unroll
    for (int j = 0; j < 4; ++j)
#pragma unroll
      for (int r = 0; r < 4; ++r) {
        const int row = m0 + wm + i * 16 + quad * 4 + r;
        const int col = n0 + wn + j * 16 + l16;
        E[(size_t)row * DD + col] = acc[i][j][r];
      }
}

// ---------------------------------------------------------------------------
extern "C" void kernel_launch(void* const* d_in, const int* in_sizes, int n_in,
                              void* d_out, int out_size, void* d_ws, size_t ws_size,
                              hipStream_t stream) {
  const float* ctx   = (const float*)d_in[0];   // [8,4096,1024] f32
  const float* query = (const float*)d_in[1];   // [8,512,1024]  f32
  const int*   mask  = (const int*)d_in[2];     // [8,4096]      int32

  float* expected = (float*)d_out;                              // [8,512,1024] f32
  float* p        = (float*)d_out + (size_t)BB * TT * DD;       // [8,512,4096] f32

  if (ws_size >= WS_NEED) {
    char* ws = (char*)d_ws;
    short* qb = (short*)(ws + OFF_QB);
    short* cb = (short*)(ws + OFF_CB);
    short* ct = (short*)(ws + OFF_CT);
    short* pb = (short*)(ws + OFF_PB);

    prep_q_kernel<<<dim3((BB * TT * DD) / (256 * 16)), 256, 0, stream>>>(query, qb);
    prep_c_kernel<<<dim3(DD / 64, SS / 64, BB), 256, 0, stream>>>(ctx, cb, ct);
    qk_kernel_f<<<dim3(SS / 128, TT / 128, BB), 256, 0, stream>>>(qb, cb, mask, p);
    softmax_kernel_f<<<dim3(BB * TT), 256, 0, stream>>>(p, pb);
    hipMemsetAsync(expected, 0, (size_t)BB * TT * DD * sizeof(float), stream);
    pv_kernel_f<<<dim3(DD / 128, TT / 128, BB * 4), 256, 0, stream>>>(pb, ct, expected);
  } else {
    // fallback: R4 proven path
    qk_kernel<<<dim3(SS / 128, TT / 128, BB), 256, 0, stream>>>(query, ctx, p);
    softmax_kernel<<<dim3(BB * TT), 256, 0, stream>>>(p, mask);
    pv_kernel<<<dim3(DD / 128, TT / 128, BB), 256, 0, stream>>>(p, ctx, expected);
  }
}